// Round 1
// baseline (34713.922 us; speedup 1.0000x reference)
//
#include <hip/hip_runtime.h>
#include <cstdint>
#include <cstddef>

// ---------------------------------------------------------------------------
// GCN(2 conv) -> 2-layer LSTM (seq=20000, H=128) -> edge head.
// Heavy part: sequential LSTM scan. Single-workgroup MFMA cell:
//   - whh0 / wih1 / whh1 as bf16 MFMA B-fragments resident in registers
//   - A operand = h replicated across all 16 M rows (D[m][n]=g[n] for all m)
//   - gx0 precomputed as [T,512] bf16; staged to LDS in 32-step chunks so
//     __syncthreads' vmcnt(0) drain is amortized (m97: barrier drains vmem)
//   - hs1 buffered in LDS, flushed per 32-step chunk
// ---------------------------------------------------------------------------

typedef __attribute__((ext_vector_type(8))) short short8x;
typedef __attribute__((ext_vector_type(4))) float f32x4;

static __device__ __forceinline__ unsigned short f2bf(float x) {
  union { float f; unsigned u; } v; v.f = x;
  unsigned r = (v.u + 0x7fffu + ((v.u >> 16) & 1u)) >> 16;   // RNE
  return (unsigned short)r;
}
static __device__ __forceinline__ float bf2f(unsigned short s) {
  union { unsigned u; float f; } v; v.u = ((unsigned)s) << 16; return v.f;
}
static __device__ __forceinline__ float sigm(float x) {
  return 1.f / (1.f + __expf(-x));
}
static __device__ __forceinline__ float tanh_(float x) {
  float e = __expf(2.f * x);            // inf-safe: e=inf -> 1, e=0 -> -1
  return 1.f - 2.f / (e + 1.f);
}

// ---------------------------------------------------------------------------
// degree / normalization
// ---------------------------------------------------------------------------
__global__ __launch_bounds__(256) void k_deg(const int* __restrict__ ei,
                                             int* __restrict__ deg, int E) {
  int e = blockIdx.x * 256 + threadIdx.x;
  if (e < E) atomicAdd(&deg[ei[E + e]], 1);
}

__global__ __launch_bounds__(256) void k_dinv(const int* __restrict__ deg,
                                              float* __restrict__ dinv, int n) {
  int i = blockIdx.x * 256 + threadIdx.x;
  if (i < n) dinv[i] = rsqrtf((float)(deg[i] + 1));   // +1 self-loop, deg>=1
}

// ---------------------------------------------------------------------------
// generic f32 GEMM: C[M,N] = A[M,128] @ B(128,N), K=128 fixed.
// bnmajor=0: B stored [128][N] (k-major, e.g. W1);  =1: B stored [N][128]
// (PyTorch weight, e.g. wih0 with C = A @ B^T).  Optional two biases.
// obf16: store C as bf16 (for the LSTM gx0 input).
// tiles: M=32 (blockIdx.x), N=64 (blockIdx.y). 256 threads.
// ---------------------------------------------------------------------------
__global__ __launch_bounds__(256) void k_gemm(
    const float* __restrict__ A, const float* __restrict__ B, void* __restrict__ C,
    int M, int N, int bnmajor, const float* __restrict__ bias0,
    const float* __restrict__ bias1, int obf16) {
  __shared__ float As[32][128];
  __shared__ float Bs[128][68];          // pad 68: bank = (4k+n)%32, conflict-free
  const int t  = threadIdx.x;
  const int m0 = blockIdx.x * 32;
  const int n0 = blockIdx.y * 64;

  for (int i = t; i < 1024; i += 256) {  // 32 rows x 32 float4
    int r = i >> 5, c4 = i & 31;
    *(float4*)&As[r][c4 * 4] = *(const float4*)(A + (size_t)(m0 + r) * 128 + c4 * 4);
  }
  if (!bnmajor) {
    for (int i = t; i < 2048; i += 256) { // 128 rows x 16 float4 (64 cols)
      int r = i >> 4, c4 = i & 15;
      float4 v = *(const float4*)(B + (size_t)r * N + n0 + c4 * 4);
      *(float4*)&Bs[r][c4 * 4] = v;
    }
  } else {
    for (int i = t; i < 2048; i += 256) { // 64 rows x 32 float4 along k, transpose
      int n = i >> 5, k4 = i & 31;
      float4 v = *(const float4*)(B + (size_t)(n0 + n) * 128 + k4 * 4);
      Bs[k4 * 4 + 0][n] = v.x; Bs[k4 * 4 + 1][n] = v.y;
      Bs[k4 * 4 + 2][n] = v.z; Bs[k4 * 4 + 3][n] = v.w;
    }
  }
  __syncthreads();

  const int nl = t & 31, mg = t >> 5;    // 32 n-lanes x 8 m-groups(4 rows)
  float acc[4][2] = {};
  for (int k = 0; k < 128; ++k) {
    float b0 = Bs[k][nl], b1 = Bs[k][nl + 32];
    float a0 = As[mg * 4 + 0][k], a1 = As[mg * 4 + 1][k];
    float a2 = As[mg * 4 + 2][k], a3 = As[mg * 4 + 3][k];
    acc[0][0] += a0 * b0; acc[0][1] += a0 * b1;
    acc[1][0] += a1 * b0; acc[1][1] += a1 * b1;
    acc[2][0] += a2 * b0; acc[2][1] += a2 * b1;
    acc[3][0] += a3 * b0; acc[3][1] += a3 * b1;
  }
  float bv0 = 0.f, bv1 = 0.f;
  if (bias0) { bv0 += bias0[n0 + nl]; bv1 += bias0[n0 + nl + 32]; }
  if (bias1) { bv0 += bias1[n0 + nl]; bv1 += bias1[n0 + nl + 32]; }
#pragma unroll
  for (int i = 0; i < 4; ++i) {
    size_t row = (size_t)(m0 + mg * 4 + i) * N;
    float v0 = acc[i][0] + bv0, v1 = acc[i][1] + bv1;
    if (obf16) {
      ((unsigned short*)C)[row + n0 + nl]      = f2bf(v0);
      ((unsigned short*)C)[row + n0 + nl + 32] = f2bf(v1);
    } else {
      ((float*)C)[row + n0 + nl]      = v0;
      ((float*)C)[row + n0 + nl + 32] = v1;
    }
  }
}

// ---------------------------------------------------------------------------
// y *= dinv[row] (in place) and acc = y  (self-loop init: out = dinv*(sum+y)+b)
// ---------------------------------------------------------------------------
__global__ __launch_bounds__(256) void k_scaleinit(float* __restrict__ y,
                                                   float* __restrict__ acc,
                                                   const float* __restrict__ dinv,
                                                   int total4) {
  int i = blockIdx.x * 256 + threadIdx.x;
  if (i >= total4) return;
  float s = dinv[i >> 5];
  float4 v = ((const float4*)y)[i];
  v.x *= s; v.y *= s; v.z *= s; v.w *= s;
  ((float4*)y)[i] = v;
  ((float4*)acc)[i] = v;
}

// acc[dst] += y[src], 32 threads (x float4) per edge
__global__ __launch_bounds__(256) void k_scatter(const float* __restrict__ y,
                                                 float* __restrict__ acc,
                                                 const int* __restrict__ ei, int E) {
  int g = blockIdx.x * 256 + threadIdx.x;
  int e = g >> 5, q = g & 31;
  if (e >= E) return;
  int s = ei[e], d = ei[E + e];
  float4 v = *(const float4*)(y + (size_t)s * 128 + q * 4);
  float* p = acc + (size_t)d * 128 + q * 4;
  atomicAdd(p + 0, v.x); atomicAdd(p + 1, v.y);
  atomicAdd(p + 2, v.z); atomicAdd(p + 3, v.w);
}

// out = (relu?)(dinv[row]*acc + bias)
__global__ __launch_bounds__(256) void k_finish(const float* __restrict__ acc,
                                                float* __restrict__ outb,
                                                const float* __restrict__ dinv,
                                                const float* __restrict__ bias,
                                                int total4, int relu) {
  int i = blockIdx.x * 256 + threadIdx.x;
  if (i >= total4) return;
  float s = dinv[i >> 5];
  float4 v = ((const float4*)acc)[i];
  float4 b = *(const float4*)(bias + (i & 31) * 4);
  v.x = v.x * s + b.x; v.y = v.y * s + b.y;
  v.z = v.z * s + b.z; v.w = v.w * s + b.w;
  if (relu) {
    v.x = fmaxf(v.x, 0.f); v.y = fmaxf(v.y, 0.f);
    v.z = fmaxf(v.z, 0.f); v.w = fmaxf(v.w, 0.f);
  }
  ((float4*)outb)[i] = v;
}

// ---------------------------------------------------------------------------
// Fused 2-layer LSTM scan. One workgroup, 512 threads (8 waves).
// gx0b: [T,512] bf16 (layer-1 input contribution incl. biases, precomputed)
// ---------------------------------------------------------------------------
#define MFMA16(a, b, c) __builtin_amdgcn_mfma_f32_16x16x32_bf16((a), (b), (c), 0, 0, 0)

__global__ __launch_bounds__(512, 2) void k_lstm(
    const unsigned short* __restrict__ gx0b,
    const float* __restrict__ whh0, const float* __restrict__ wih1,
    const float* __restrict__ whh1, const float* __restrict__ bih1,
    const float* __restrict__ bhh1, float* __restrict__ hs1,
    float* __restrict__ hncn, int T) {
  __shared__ __align__(16) unsigned short h0buf[128];   // bf16 h of layer 1
  __shared__ __align__(16) unsigned short h1buf[128];   // bf16 h of layer 2
  __shared__ float gbuf[512];                            // matvec results
  __shared__ __align__(16) unsigned short gxlds[32 * 512]; // gx0 chunk (32 KB)
  __shared__ __align__(16) float hslds[32 * 128];        // hs1 chunk (16 KB)

  const int tid  = threadIdx.x;
  const int lane = tid & 63;
  const int wave = tid >> 6;     // 0..7, owns n-tiles [4w,4w+4)
  const int col  = lane & 15;    // n within 16-tile / C col
  const int kg   = lane >> 4;    // k-group-of-8 within 32-k tile

  // --- preload weight B-fragments (bf16): reg j = W[n][32kt + 8kg + j] ---
  short8x fr0[4][4], fr1[4][4], fr2[4][4];  // [nt][kt]
  {
    const int nbase = wave * 64 + col;
#pragma unroll
    for (int nt = 0; nt < 4; ++nt) {
#pragma unroll
      for (int kt = 0; kt < 4; ++kt) {
        const int n  = nbase + nt * 16;
        const int k0 = kt * 32 + kg * 8;
        const float* p0 = whh0 + (size_t)n * 128 + k0;
        const float* p1 = wih1 + (size_t)n * 128 + k0;
        const float* p2 = whh1 + (size_t)n * 128 + k0;
        short8x a, b, c;
#pragma unroll
        for (int j = 0; j < 8; ++j) {
          a[j] = (short)f2bf(p0[j]);
          b[j] = (short)f2bf(p1[j]);
          c[j] = (short)f2bf(p2[j]);
        }
        fr0[nt][kt] = a; fr1[nt][kt] = b; fr2[nt][kt] = c;
      }
    }
  }

  float c0 = 0.f, c1 = 0.f, h0f = 0.f, h1f = 0.f;
  float b2i = 0.f, b2f = 0.f, b2g = 0.f, b2o = 0.f;
  if (tid < 128) {
    b2i = bih1[tid]       + bhh1[tid];
    b2f = bih1[tid + 128] + bhh1[tid + 128];
    b2g = bih1[tid + 256] + bhh1[tid + 256];
    b2o = bih1[tid + 384] + bhh1[tid + 384];
    h0buf[tid] = 0; h1buf[tid] = 0;
  }
  __syncthreads();

  for (int t = 0; t < T; ++t) {
    // ---- stage gx0 chunk (32 steps = 32 KB bf16); barrier A orders it ----
    if ((t & 31) == 0) {
      const short8x* src = (const short8x*)(gx0b + (size_t)t * 512);
      short8x* dst = (short8x*)gxlds;
#pragma unroll
      for (int r = 0; r < 4; ++r) {
        int i = tid + 512 * r;   // 2048 x 16B
        dst[i] = src[i];
      }
    }

    // ---- MV1: g = whh0 @ h0 (A = h0 replicated over M rows) ----
    f32x4 acc0 = {0.f, 0.f, 0.f, 0.f}, acc1 = acc0, acc2 = acc0, acc3 = acc0;
#pragma unroll
    for (int kt = 0; kt < 4; ++kt) {
      short8x a = *(const short8x*)(h0buf + kt * 32 + kg * 8);
      acc0 = MFMA16(a, fr0[0][kt], acc0);
      acc1 = MFMA16(a, fr0[1][kt], acc1);
      acc2 = MFMA16(a, fr0[2][kt], acc2);
      acc3 = MFMA16(a, fr0[3][kt], acc3);
    }
    if (lane < 16) {
      gbuf[wave * 64 + 0  + lane] = acc0[0];
      gbuf[wave * 64 + 16 + lane] = acc1[0];
      gbuf[wave * 64 + 32 + lane] = acc2[0];
      gbuf[wave * 64 + 48 + lane] = acc3[0];
    }
    __syncthreads();   // barrier A

    // ---- layer-1 gates (threads 0..127 keep c0) ----
    if (tid < 128) {
      const unsigned short* gx = gxlds + (size_t)(t & 31) * 512 + tid;
      float gi = bf2f(gx[0])   + gbuf[tid];
      float gf = bf2f(gx[128]) + gbuf[tid + 128];
      float gg = bf2f(gx[256]) + gbuf[tid + 256];
      float go = bf2f(gx[384]) + gbuf[tid + 384];
      float iv = sigm(gi), fv = sigm(gf), gv = tanh_(gg), ov = sigm(go);
      c0 = fv * c0 + iv * gv;
      h0f = ov * tanh_(c0);
      h0buf[tid] = f2bf(h0f);
    }
    __syncthreads();   // barrier B

    // ---- MV2+MV3: g2 = wih1 @ h0new + whh1 @ h1 ----
    acc0 = (f32x4){0.f, 0.f, 0.f, 0.f}; acc1 = acc0; acc2 = acc0; acc3 = acc0;
#pragma unroll
    for (int kt = 0; kt < 4; ++kt) {
      short8x a = *(const short8x*)(h0buf + kt * 32 + kg * 8);
      acc0 = MFMA16(a, fr1[0][kt], acc0);
      acc1 = MFMA16(a, fr1[1][kt], acc1);
      acc2 = MFMA16(a, fr1[2][kt], acc2);
      acc3 = MFMA16(a, fr1[3][kt], acc3);
    }
#pragma unroll
    for (int kt = 0; kt < 4; ++kt) {
      short8x a = *(const short8x*)(h1buf + kt * 32 + kg * 8);
      acc0 = MFMA16(a, fr2[0][kt], acc0);
      acc1 = MFMA16(a, fr2[1][kt], acc1);
      acc2 = MFMA16(a, fr2[2][kt], acc2);
      acc3 = MFMA16(a, fr2[3][kt], acc3);
    }
    if (lane < 16) {
      gbuf[wave * 64 + 0  + lane] = acc0[0];
      gbuf[wave * 64 + 16 + lane] = acc1[0];
      gbuf[wave * 64 + 32 + lane] = acc2[0];
      gbuf[wave * 64 + 48 + lane] = acc3[0];
    }
    __syncthreads();   // barrier C

    // ---- layer-2 gates ----
    if (tid < 128) {
      float gi = gbuf[tid]       + b2i;
      float gf = gbuf[tid + 128] + b2f;
      float gg = gbuf[tid + 256] + b2g;
      float go = gbuf[tid + 384] + b2o;
      float iv = sigm(gi), fv = sigm(gf), gv = tanh_(gg), ov = sigm(go);
      c1 = fv * c1 + iv * gv;
      h1f = ov * tanh_(c1);
      h1buf[tid] = f2bf(h1f);
      hslds[(t & 31) * 128 + tid] = h1f;
    }
    __syncthreads();   // barrier D

    // ---- flush hs1 chunk ----
    if ((t & 31) == 31 || t == T - 1) {
      int t0 = t & ~31;
      int cnt = ((t & 31) + 1) * 32;          // float4 count
      float4* dst = (float4*)(hs1 + (size_t)t0 * 128);
      for (int i = tid; i < cnt; i += 512) dst[i] = ((const float4*)hslds)[i];
    }
  }

  if (tid < 128) {                // hn = [h0T, h1T], cn = [c0T, c1T]
    hncn[tid]       = h0f;
    hncn[128 + tid] = h1f;
    hncn[256 + tid] = c0;
    hncn[384 + tid] = c1;
  }
}

// ---------------------------------------------------------------------------
// edge head: src/dst gather-writes, edge_emb = ef@eW+eb, pred = combined.cW+cb
// one wave per edge iteration; lane l owns components {2l,2l+1} / emb {l,l+64}
// ---------------------------------------------------------------------------
__global__ __launch_bounds__(256) void k_edge(
    const float* __restrict__ S, const int* __restrict__ ei,
    const float* __restrict__ ef, const float* __restrict__ eW,
    const float* __restrict__ eb, const float* __restrict__ cW,
    const float* __restrict__ cb, float* __restrict__ out, int E) {
  const int lane = threadIdx.x & 63;
  const int gw   = (blockIdx.x * 256 + threadIdx.x) >> 6;
  const int nw   = gridDim.x * 4;
  const size_t so = (size_t)E + 512;                  // src rows offset
  const size_t doff = so + (size_t)E * 128;           // dst rows offset

  const float cs0 = cW[2 * lane], cs1 = cW[2 * lane + 1];
  const float cd0 = cW[128 + 2 * lane], cd1 = cW[128 + 2 * lane + 1];
  const float ce0 = cW[256 + lane], ce1 = cW[320 + lane];
  const float eb0 = eb[lane], eb1 = eb[lane + 64];
  const float cbv = cb[0];

  for (int e = gw; e < E; e += nw) {
    int s = ei[e], d = ei[E + e];
    float2 vs = *(const float2*)(S + (size_t)s * 128 + 2 * lane);
    float2 vd = *(const float2*)(S + (size_t)d * 128 + 2 * lane);
    *(float2*)(out + so + (size_t)e * 128 + 2 * lane) = vs;
    *(float2*)(out + doff + (size_t)e * 128 + 2 * lane) = vd;

    float a0 = eb0, a1 = eb1;
    const float* efr = ef + (size_t)e * 32;
#pragma unroll
    for (int k = 0; k < 32; ++k) {
      float x = efr[k];
      a0 += x * eW[k * 128 + lane];
      a1 += x * eW[k * 128 + 64 + lane];
    }
    float p = vs.x * cs0 + vs.y * cs1 + vd.x * cd0 + vd.y * cd1 + a0 * ce0 + a1 * ce1;
#pragma unroll
    for (int m = 32; m; m >>= 1) p += __shfl_xor(p, m, 64);
    if (lane == 0) out[e] = p + cbv;
  }
}

// ---------------------------------------------------------------------------
extern "C" void kernel_launch(void* const* d_in, const int* in_sizes, int n_in,
                              void* d_out, int out_size, void* d_ws, size_t ws_size,
                              hipStream_t stream) {
  const float* x    = (const float*)d_in[0];
  const int*   ei   = (const int*)d_in[1];
  const float* ef   = (const float*)d_in[2];
  const float* W1   = (const float*)d_in[3];
  const float* b1   = (const float*)d_in[4];
  const float* W2   = (const float*)d_in[5];
  const float* b2   = (const float*)d_in[6];
  const float* wih0 = (const float*)d_in[7];
  const float* whh0 = (const float*)d_in[8];
  const float* bih0 = (const float*)d_in[9];
  const float* bhh0 = (const float*)d_in[10];
  const float* wih1 = (const float*)d_in[11];
  const float* whh1 = (const float*)d_in[12];
  const float* bih1 = (const float*)d_in[13];
  const float* bhh1 = (const float*)d_in[14];
  const float* eW   = (const float*)d_in[15];
  const float* eb   = (const float*)d_in[16];
  const float* cW   = (const float*)d_in[17];
  const float* cb   = (const float*)d_in[18];

  const int nN = in_sizes[0] / 128;   // 20000
  const int E  = in_sizes[1] / 2;     // 320000

  char* ws = (char*)d_ws;
  float* dinv          = (float*)ws;                       //  80 KB slot
  int*   deg           = (int*)(ws + 81920);               //  80 KB slot
  float* buf1          = (float*)(ws + 163840);            // [nN,128]
  float* buf2          = buf1 + (size_t)nN * 128;          // [nN,128]
  float* buf3          = buf2 + (size_t)nN * 128;          // [nN,128]
  unsigned short* G    = (unsigned short*)(buf3 + (size_t)nN * 128); // [nN,512] bf16
  float* S             = (float*)(G + (size_t)nN * 512);   // [nN,128] hs1
  float* out           = (float*)d_out;

  const int total4 = nN * 32;
  const int gElem  = (total4 + 255) / 256;
  const dim3 g128(nN / 32, 2);   // N=128 GEMMs
  const dim3 g512(nN / 32, 8);   // N=512 GEMM

  // degree / normalization
  hipMemsetAsync(deg, 0, nN * sizeof(int), stream);
  k_deg<<<(E + 255) / 256, 256, 0, stream>>>(ei, deg, E);
  k_dinv<<<(nN + 255) / 256, 256, 0, stream>>>(deg, dinv, nN);

  // conv1: h = relu(dinv*(scatter(x@W1 * dinv)) + b1)
  k_gemm<<<g128, 256, 0, stream>>>(x, W1, buf1, nN, 128, 0, nullptr, nullptr, 0);
  k_scaleinit<<<gElem, 256, 0, stream>>>(buf1, buf2, dinv, total4);
  k_scatter<<<(E * 32 + 255) / 256, 256, 0, stream>>>(buf1, buf2, ei, E);
  k_finish<<<gElem, 256, 0, stream>>>(buf2, buf3, dinv, b1, total4, 1);

  // conv2 (no relu)
  k_gemm<<<g128, 256, 0, stream>>>(buf3, W2, buf1, nN, 128, 0, nullptr, nullptr, 0);
  k_scaleinit<<<gElem, 256, 0, stream>>>(buf1, buf2, dinv, total4);
  k_scatter<<<(E * 32 + 255) / 256, 256, 0, stream>>>(buf1, buf2, ei, E);
  k_finish<<<gElem, 256, 0, stream>>>(buf2, buf3, dinv, b2, total4, 0);

  // gx0 = h2 @ wih0^T + (bih0 + bhh0), stored bf16
  k_gemm<<<g512, 256, 0, stream>>>(buf3, wih0, G, nN, 512, 1, bih0, bhh0, 1);

  // fused 2-layer LSTM scan (single workgroup); hn/cn written into d_out
  k_lstm<<<1, 512, 0, stream>>>(G, whh0, wih1, whh1, bih1, bhh1, S, out + (size_t)E, nN);

  // edge head
  k_edge<<<2048, 256, 0, stream>>>(S, ei, ef, eW, eb, cW, cb, out, E);
}